// Round 2
// baseline (511.597 us; speedup 1.0000x reference)
//
#include <hip/hip_runtime.h>

// LSTM B=1024,T=512,F=40,H=50. r8 (280us dispatch) showed the barrier count
// wasn't the bottleneck. r9 removes the two real chain terms:
//  (1) IN-PLACE pointwise: D-frag lane (m16,q) of tile i already holds all 4
//      gates of unit 4*(t0+i)+q batch m16 -> no gate exchange at all. The
//      sh_wg roundtrip (write+lgkmcnt+read, ~250cy + bank conflicts) is gone;
//      cost is NT units of transcendentals serialized per owner lane.
//  (2) RAW barrier: __syncthreads() drains vmcnt(0), so the per-step x
//      prefetch (global load) was re-serialized into EVERY step. We emit
//      "s_waitcnt lgkmcnt(0); s_barrier" only -- LDS visibility is the only
//      cross-wave requirement; the prefetch value is register-private and the
//      compiler inserts its own vmcnt wait at its use 2 steps later.
//
// GEMM per step: G^T[208,16] = W'[208,96] @ [x|h]^T[96,16], rows' =
// 4*unit+gate, 13 M-tiles split 3/3/3/4 over 4 waves, 3 K-chunks
// (K=96: x 0..39 | h 40..89 | pad). Owner lanes m16<kMB update c (register,
// 4 per lane) and write h bf16 straight into the next panel.

constexpr int kT    = 512;
constexpr int kF    = 40;
constexpr int kH    = 50;
constexpr int kMB   = 2;      // real batches per block
constexpr int kRowS = 104;    // combined panel row stride in shorts (208 B)

typedef __attribute__((ext_vector_type(8))) short bf16x8;
typedef __attribute__((ext_vector_type(4))) float f32x4;

__device__ __forceinline__ unsigned short f2bf(float f) {
    union { float f; unsigned u; } v; v.f = f;
    return (unsigned short)((v.u + 0x7FFFu + ((v.u >> 16) & 1u)) >> 16);
}
__device__ __forceinline__ float fast_sigmoid(float v) {
    return __builtin_amdgcn_rcpf(1.f + __expf(-v));
}
__device__ __forceinline__ float fast_tanh(float v) {
    return 1.f - 2.f * __builtin_amdgcn_rcpf(__expf(2.f * v) + 1.f);
}

__global__ __launch_bounds__(256, 2)
void lstm_mfma_inplace(
    const float* __restrict__ x,      // [B,T,F]
    const float* __restrict__ W_ih,   // [4H,F]
    const float* __restrict__ W_hh,   // [4H,H]
    const float* __restrict__ b_ih,   // [4H]
    const float* __restrict__ b_hh,   // [4H]
    const float* __restrict__ W1,     // [10,H]
    const float* __restrict__ b1,     // [10]
    const float* __restrict__ W2,     // [1,10]
    const float* __restrict__ b2,     // [1]
    float* __restrict__ out)          // [B]
{
    const int tid  = threadIdx.x;
    const int lane = tid & 63;
    const int wave = tid >> 6;
    const int bb   = blockIdx.x;
    const int m16  = lane & 15;    // D col = batch
    const int q    = lane >> 4;    // quad

    __shared__ __align__(16) short sh_comb[2][16][kRowS]; // [x|h|pad] bf16
    __shared__ float sh_hf[kMB][kH + 2];                  // final h fp32
    __shared__ float sh_head[kMB][10];

    const int t0 = (wave == 3) ? 9 : wave * 3;   // first tile of this wave
    const int NT = (wave == 3) ? 4 : 3;          // tiles 3/3/3/4 = 13

    // zero the combined panels (pads + batch cols 2..15 stay 0 forever)
    { int* z = (int*)sh_comb; for (int i = tid; i < 1664; i += 256) z[i] = 0; }

    // ---- A-frag weights (registers) + bias for C operand ----
    bf16x8 wa[4][3];
    f32x4  bias4[4];
    const int uA = m16 >> 2, gA = m16 & 3;
#pragma unroll
    for (int i = 0; i < 4; ++i) {
        const int tl = t0 + i;
        const int unitA = 4 * tl + uA;
        const bool live = (i < NT) && (unitA < kH);
        const int orow = live ? (unitA + 50 * gA) : 0;
#pragma unroll
        for (int kk = 0; kk < 3; ++kk) {
            bf16x8 v;
#pragma unroll
            for (int j = 0; j < 8; ++j) {
                const int k = kk * 32 + q * 8 + j;
                float wv = 0.f;
                if (live) {
                    if (k < kF)           wv = W_ih[orow * kF + k];
                    else if (k < kF + kH) wv = W_hh[orow * kH + (k - kF)];
                }
                v[j] = (short)f2bf(wv);
            }
            wa[i][kk] = v;
        }
        const int uD = 4 * tl + q;
#pragma unroll
        for (int r = 0; r < 4; ++r)
            bias4[i][r] = (i < NT && uD < kH)
                        ? (b_ih[uD + 50 * r] + b_hh[uD + 50 * r]) : 0.f;
    }

    // ---- in-place pointwise owners: lanes m16<kMB, tile i -> unit 4*(t0+i)+q
    const bool ow = (m16 < kMB);
    float cst[4], hv[4];
#pragma unroll
    for (int i = 0; i < 4; ++i) {
        cst[i] = (ow && (4 * (t0 + i) + q == 0)) ? 1.f : 0.f;  // c0[:,0]=1
        hv[i]  = 0.f;
    }

    // ---- x stagers: lanes 32..41 of each wave own (batch xm, chunk xd) ----
    const bool xst = (lane >= 32 && lane < 42);
    const int  fid = xst ? (wave * 10 + (lane - 32)) : 0;   // 0..39
    const int  xm = fid / 20, xd = fid % 20;
    const float* xrow = x + ((size_t)(bb * kMB + xm) * kT) * kF + 2 * xd;

    float2 pa = {0.f, 0.f}, pb = {0.f, 0.f};
    __syncthreads();                              // zero-init done
    if (xst) {
        float2 v0 = *(const float2*)xrow;         // x_0
        unsigned pk = (unsigned)f2bf(v0.x) | ((unsigned)f2bf(v0.y) << 16);
        *(unsigned*)&sh_comb[0][xm][2 * xd] = pk;
        pa = *(const float2*)(xrow + (size_t)1 * kF);   // x_1 (used t=0)
        pb = *(const float2*)(xrow + (size_t)2 * kF);   // x_2 (used t=1)
    }
    __syncthreads();

    // ---- one step; CUR = t&1 compile-time via 2-phase unroll ----
    auto step = [&](int t, int CUR, float2& pf) {
        const short* rowp = &sh_comb[CUR][m16][0];
        bf16x8 bv0 = *(const bf16x8*)(rowp +      q * 8);   // k  0..31
        bf16x8 bv1 = *(const bf16x8*)(rowp + 32 + q * 8);   // k 32..63
        bf16x8 bv2 = *(const bf16x8*)(rowp + 64 + q * 8);   // k 64..95
        f32x4 dd[4];
#pragma unroll
        for (int i = 0; i < 4; ++i) {
            if (i < NT) {                                   // wave-uniform
                f32x4 d = bias4[i];
                d = __builtin_amdgcn_mfma_f32_16x16x32_bf16(wa[i][0], bv0, d, 0, 0, 0);
                d = __builtin_amdgcn_mfma_f32_16x16x32_bf16(wa[i][1], bv1, d, 0, 0, 0);
                d = __builtin_amdgcn_mfma_f32_16x16x32_bf16(wa[i][2], bv2, d, 0, 0, 0);
                dd[i] = d;
            }
        }
        short* nbuf = &sh_comb[CUR ^ 1][0][0];
        if (xst) {                                          // issue early
            if (t + 1 < kT) {
                unsigned pk = (unsigned)f2bf(pf.x) | ((unsigned)f2bf(pf.y) << 16);
                *(unsigned*)&nbuf[xm * kRowS + 2 * xd] = pk;
            }
            if (t + 3 < kT)                                 // distance-2 prefetch
                pf = *(const float2*)(xrow + (size_t)(t + 3) * kF);
        }
        if (ow) {
            // gates of (batch m16, unit 4*(t0+i)+q) are dd[i][0..3] IN LANE
#pragma unroll
            for (int i = 0; i < 4; ++i) {
                const int u = 4 * (t0 + i) + q;
                if (i < NT && u < kH) {
                    f32x4 g = dd[i];
                    float i_s = fast_sigmoid(g[0]);
                    float f_s = fast_sigmoid(g[1]);
                    float g_t = fast_tanh   (g[2]);
                    float o_s = fast_sigmoid(g[3]);
                    cst[i] = fmaf(f_s, cst[i], i_s * g_t);
                    hv[i]  = o_s * fast_tanh(cst[i]);
                    if (t + 1 < kT)
                        nbuf[m16 * kRowS + kF + u] = (short)f2bf(hv[i]);
                }
            }
        }
        // raw barrier: LDS-only drain. NO vmcnt(0) -- keep x prefetch in
        // flight across the barrier (its use is 2 steps later; compiler
        // inserts the vmcnt wait at the use).
        asm volatile("s_waitcnt lgkmcnt(0)\n\ts_barrier" ::: "memory");
    };

    for (int t = 0; t < kT; t += 2) {
        step(t,     0, pa);
        step(t + 1, 1, pb);
    }

    // ---- head: relu(h @ W1.T + b1) @ W2.T + b2 + x[b, T-1, 0] ----
    if (ow) {
#pragma unroll
        for (int i = 0; i < 4; ++i) {
            const int u = 4 * (t0 + i) + q;
            if (i < NT && u < kH) sh_hf[m16][u] = hv[i];
        }
    }
    __syncthreads();
    if (tid < kMB * 10) {
        const int m = tid / 10, j = tid % 10;
        float acc = b1[j];
#pragma unroll
        for (int k = 0; k < kH; ++k) acc = fmaf(sh_hf[m][k], W1[j * kH + k], acc);
        sh_head[m][j] = fmaxf(acc, 0.f);
    }
    __syncthreads();
    if (tid < kMB) {
        float acc = b2[0];
#pragma unroll
        for (int j2 = 0; j2 < 10; ++j2) acc = fmaf(sh_head[tid][j2], W2[j2], acc);
        const int bidx = bb * kMB + tid;
        out[bidx] = acc + x[((size_t)bidx * kT + (kT - 1)) * kF];
    }
}

extern "C" void kernel_launch(void* const* d_in, const int* in_sizes, int n_in,
                              void* d_out, int out_size, void* d_ws, size_t ws_size,
                              hipStream_t stream) {
    const float* x    = (const float*)d_in[0];
    const float* W_ih = (const float*)d_in[1];
    const float* W_hh = (const float*)d_in[2];
    const float* b_ih = (const float*)d_in[3];
    const float* b_hh = (const float*)d_in[4];
    const float* W1   = (const float*)d_in[5];
    const float* b1   = (const float*)d_in[6];
    const float* W2   = (const float*)d_in[7];
    const float* b2   = (const float*)d_in[8];
    float* out = (float*)d_out;

    lstm_mfma_inplace<<<dim3(1024 / kMB), dim3(256), 0, stream>>>(
        x, W_ih, W_hh, b_ih, b_hh, W1, b1, W2, b2, out);
}

// Round 3
// 358.487 us; speedup vs baseline: 1.4271x; 1.4271x over previous
//
#include <hip/hip_runtime.h>

// LSTM B=1024,T=512,F=40,H=50. r7 (267us dispatch) = best. r8 (wave-local
// exchange, 1 barrier) = 280; r9 (in-place pointwise) = 440 -- proved
// transcendental ISSUE per wave is first-order (wave-granular quarter-rate
// pipe), and that the 1.26e7 bank conflicts are sh_comb b128 reads (~4%),
// not sh_g. r10 = r7 EXACTLY + one change: in-loop barriers are raw
// "s_waitcnt lgkmcnt(0); s_barrier" -- __syncthreads() drains vmcnt(0),
// re-serializing the xst lanes' in-flight global x-prefetch (~200cy L2
// latency) into EVERY step's chain. Cross-wave data (sh_g, sh_comb) is all
// LDS -> lgkmcnt-only is sufficient; the prefetch value is register-private,
// compiler waits vmcnt at its use 2 steps later.
//
// GEMM per step: G^T[208,16] = W'[208,96] @ [x|h]^T[96,16], rows' =
// 4*unit+gate (i,f,g,o interleaved), 13 M-tiles split 3/3/3/4 over 4 waves,
// 3 K-chunks (K=96: x 0..39 | h 40..89 | pad). D lane (m16,q) holds gates
// r=0..3 of unit 4*tile+q, batch col m16 (only m16<2 real). Pointwise on
// 100 dense lanes (waves 0-1), x stagers in wave 2, distance-2 prefetch.

constexpr int kT   = 512;
constexpr int kF   = 40;
constexpr int kH   = 50;
constexpr int kMB  = 2;      // real batches per block
constexpr int kRowS = 104;   // combined panel row stride in shorts (208 B)
constexpr int kGRow = 208;   // sh_g row stride in dwords (13 tiles * 16)

typedef __attribute__((ext_vector_type(8))) short bf16x8;
typedef __attribute__((ext_vector_type(4))) float f32x4;

__device__ __forceinline__ unsigned short f2bf(float f) {
    union { float f; unsigned u; } v; v.f = f;
    return (unsigned short)((v.u + 0x7FFFu + ((v.u >> 16) & 1u)) >> 16);
}
__device__ __forceinline__ float fast_sigmoid(float v) {
    return __builtin_amdgcn_rcpf(1.f + __expf(-v));
}
__device__ __forceinline__ float fast_tanh(float v) {
    return 1.f - 2.f * __builtin_amdgcn_rcpf(__expf(2.f * v) + 1.f);
}

__global__ __launch_bounds__(256, 2)
void lstm_mfma_rawbar(
    const float* __restrict__ x,      // [B,T,F]
    const float* __restrict__ W_ih,   // [4H,F]
    const float* __restrict__ W_hh,   // [4H,H]
    const float* __restrict__ b_ih,   // [4H]
    const float* __restrict__ b_hh,   // [4H]
    const float* __restrict__ W1,     // [10,H]
    const float* __restrict__ b1,     // [10]
    const float* __restrict__ W2,     // [1,10]
    const float* __restrict__ b2,     // [1]
    float* __restrict__ out)          // [B]
{
    const int tid  = threadIdx.x;
    const int lane = tid & 63;
    const int wave = tid >> 6;
    const int bb   = blockIdx.x;
    const int m16  = lane & 15;    // D col = batch
    const int q    = lane >> 4;    // quad

    __shared__ short sh_comb[2][16][kRowS];  // [x(0..39)|h(40..89)|pad] bf16
    __shared__ float sh_g[kMB][kGRow];       // gate pre-acts, rows' = 4u+r
    __shared__ float sh_hf[kMB][kH + 2];     // final h fp32
    __shared__ float sh_head[kMB][10];

    const int t0 = (wave == 3) ? 9 : wave * 3;   // first tile of this wave
    const int NT = (wave == 3) ? 4 : 3;          // tiles 3/3/3/4 = 13

    // zero the combined panels (pads + batch cols 2..15 stay 0 forever)
    { int* z = (int*)sh_comb; for (int i = tid; i < 1664; i += 256) z[i] = 0; }

    // ---- A-frag weights (registers) + bias for C operand ----
    bf16x8 wa[4][3];
    float  bias[4][4];
    const int uA = m16 >> 2, gA = m16 & 3;
#pragma unroll
    for (int i = 0; i < 4; ++i) {
        const int tl = t0 + i;
        const int unitA = 4 * tl + uA;
        const bool live = (i < NT) && (unitA < kH);
        const int orow = live ? (unitA + 50 * gA) : 0;
#pragma unroll
        for (int kk = 0; kk < 3; ++kk) {
            bf16x8 v;
#pragma unroll
            for (int j = 0; j < 8; ++j) {
                const int k = kk * 32 + q * 8 + j;
                float wv = 0.f;
                if (live) {
                    if (k < kF)           wv = W_ih[orow * kF + k];
                    else if (k < kF + kH) wv = W_hh[orow * kH + (k - kF)];
                }
                v[j] = (short)f2bf(wv);
            }
            wa[i][kk] = v;
        }
        const int uD = 4 * tl + q;
#pragma unroll
        for (int r = 0; r < 4; ++r)
            bias[i][r] = (i < NT && uD < kH)
                       ? (b_ih[uD + 50 * r] + b_hh[uD + 50 * r]) : 0.f;
    }

    // ---- dense pointwise owners: tid<100 -> (batch pm, unit pu) ----
    const bool pw = (tid < kMB * kH);
    const int  pm = pw ? (tid / kH) : 0;
    const int  pu = pw ? (tid % kH) : 0;
    float c     = (pw && pu == 0) ? 1.f : 0.f;   // c0[:,0] = 1
    float lasth = 0.f;

    // ---- x stagers: wave 2 lanes 0..39 own (batch xm, float2 chunk xd) ----
    const bool xs = (tid >= 128 && tid < 128 + kMB * 20);
    const int  xi = xs ? (tid - 128) : 0;
    const int  xm = xi / 20, xd = xi % 20;
    const float* xrow = x + ((size_t)(bb * kMB + xm) * kT) * kF + 2 * xd;

    float2 pa = {0.f, 0.f}, pb = {0.f, 0.f};
    __syncthreads();                              // zero-init done
    if (xs) {
        float2 v0 = *(const float2*)xrow;         // x_0
        unsigned pk = (unsigned)f2bf(v0.x) | ((unsigned)f2bf(v0.y) << 16);
        *(unsigned*)&sh_comb[0][xm][2 * xd] = pk;
        pa = *(const float2*)(xrow + (size_t)1 * kF);   // x_1 (used t=0)
        pb = *(const float2*)(xrow + (size_t)2 * kF);   // x_2 (used t=1)
    }
    __syncthreads();

    // ---- one step; CUR = t&1 compile-time via 2-phase unroll ----
    auto step = [&](int t, int CUR, float2& pf) {
        const short* rowp = &sh_comb[CUR][m16][0];
        bf16x8 bv0 = *(const bf16x8*)(rowp +      q * 8);   // k  0..31
        bf16x8 bv1 = *(const bf16x8*)(rowp + 32 + q * 8);   // k 32..63
        bf16x8 bv2 = *(const bf16x8*)(rowp + 64 + q * 8);   // k 64..95
#pragma unroll
        for (int i = 0; i < 4; ++i) {
            if (i < NT) {                                   // wave-uniform
                f32x4 d;
                d[0] = bias[i][0]; d[1] = bias[i][1];
                d[2] = bias[i][2]; d[3] = bias[i][3];
                d = __builtin_amdgcn_mfma_f32_16x16x32_bf16(wa[i][0], bv0, d, 0, 0, 0);
                d = __builtin_amdgcn_mfma_f32_16x16x32_bf16(wa[i][1], bv1, d, 0, 0, 0);
                d = __builtin_amdgcn_mfma_f32_16x16x32_bf16(wa[i][2], bv2, d, 0, 0, 0);
                if (m16 < kMB)                              // 2 real cols only
                    *(f32x4*)&sh_g[m16][16 * (t0 + i) + 4 * q] = d;
            }
        }
        // barrier A: sh_g ready. LDS-only drain -- do NOT wait vmcnt(0);
        // the xst global prefetch stays in flight across the barrier.
        asm volatile("s_waitcnt lgkmcnt(0)\n\ts_barrier" ::: "memory");

        short* nbuf = &sh_comb[CUR ^ 1][0][0];
        if (pw) {
            f32x4 g = *(const f32x4*)&sh_g[pm][4 * pu];     // i,f,g,o of unit pu
            float i_s = fast_sigmoid(g[0]);
            float f_s = fast_sigmoid(g[1]);
            float g_t = fast_tanh   (g[2]);
            float o_s = fast_sigmoid(g[3]);
            c = fmaf(f_s, c, i_s * g_t);
            lasth = o_s * fast_tanh(c);
            if (t + 1 < kT)
                nbuf[pm * kRowS + kF + pu] = (short)f2bf(lasth);
        } else if (xs) {
            if (t + 1 < kT) {
                unsigned pk = (unsigned)f2bf(pf.x) | ((unsigned)f2bf(pf.y) << 16);
                *(unsigned*)&nbuf[xm * kRowS + 2 * xd] = pk;
            }
            if (t + 3 < kT)                                  // distance-2 prefetch
                pf = *(const float2*)(xrow + (size_t)(t + 3) * kF);
        }
        // barrier B: next panel ready. LDS-only drain again.
        asm volatile("s_waitcnt lgkmcnt(0)\n\ts_barrier" ::: "memory");
    };

    for (int t = 0; t < kT; t += 2) {
        step(t,     0, pa);
        step(t + 1, 1, pb);
    }

    // ---- head: relu(h @ W1.T + b1) @ W2.T + b2 + x[b, T-1, 0] ----
    if (pw) sh_hf[pm][pu] = lasth;
    __syncthreads();
    if (tid < kMB * 10) {
        const int m = tid / 10, j = tid % 10;
        float acc = b1[j];
#pragma unroll
        for (int k = 0; k < kH; ++k) acc = fmaf(sh_hf[m][k], W1[j * kH + k], acc);
        sh_head[m][j] = fmaxf(acc, 0.f);
    }
    __syncthreads();
    if (tid < kMB) {
        float acc = b2[0];
#pragma unroll
        for (int j2 = 0; j2 < 10; ++j2) acc = fmaf(sh_head[tid][j2], W2[j2], acc);
        const int bidx = bb * kMB + tid;
        out[bidx] = acc + x[((size_t)bidx * kT + (kT - 1)) * kF];
    }
}

extern "C" void kernel_launch(void* const* d_in, const int* in_sizes, int n_in,
                              void* d_out, int out_size, void* d_ws, size_t ws_size,
                              hipStream_t stream) {
    const float* x    = (const float*)d_in[0];
    const float* W_ih = (const float*)d_in[1];
    const float* W_hh = (const float*)d_in[2];
    const float* b_ih = (const float*)d_in[3];
    const float* b_hh = (const float*)d_in[4];
    const float* W1   = (const float*)d_in[5];
    const float* b1   = (const float*)d_in[6];
    const float* W2   = (const float*)d_in[7];
    const float* b2   = (const float*)d_in[8];
    float* out = (float*)d_out;

    lstm_mfma_rawbar<<<dim3(1024 / kMB), dim3(256), 0, stream>>>(
        x, W_ih, W_hh, b_ih, b_hh, W1, b1, W2, b2, out);
}